// Round 7
// baseline (351.493 us; speedup 1.0000x reference)
//
#include <hip/hip_runtime.h>
#include <hip/hip_cooperative_groups.h>

namespace cg = cooperative_groups;

#define B_DIM 512
#define F_DIM 128
#define L_DIM 1024
#define K_CLS 8
#define EPS 1e-5f
#define NROWS (B_DIM * F_DIM)     // 65536
#define GRID  1024
#define RPB   (NROWS / GRID)      // 64 rows per block

typedef float vf4 __attribute__((ext_vector_type(4)));

// st layout (floats): [0,NROWS) psum[f*512+b] | [NROWS,2N) psq | then scale/shift [k*128+f]
#define ST_SQ    NROWS
#define ST_SCALE (2 * NROWS)
#define ST_SHIFT (2 * NROWS + K_CLS * F_DIM)

__global__ __launch_bounds__(256, 4) void cbn_fused(const float* __restrict__ x,
                                                    const int* __restrict__ labels,
                                                    const float* __restrict__ weight,
                                                    const float* __restrict__ bias,
                                                    float* __restrict__ st,
                                                    float* __restrict__ y) {
    const int blk  = blockIdx.x;
    const int tid  = threadIdx.x;
    const int wave = tid >> 6;
    const int lane = tid & 63;
    const int r0   = blk * RPB;              // 64 consecutive rows, all same b

    // ---- Phase 1: per-row partial sums; one wave handles 16 rows ----
    for (int i = 0; i < RPB / 4; ++i) {
        const int row = r0 + wave * (RPB / 4) + i;
        const vf4* x4 = reinterpret_cast<const vf4*>(x) + (size_t)row * (L_DIM / 4);
        float s = 0.f, s2 = 0.f;
#pragma unroll
        for (int j = 0; j < 4; ++j) {
            vf4 v = x4[j * 64 + lane];       // normal load -> fills MALL
            s  += v.x + v.y + v.z + v.w;
            s2 += v.x * v.x + v.y * v.y + v.z * v.z + v.w * v.w;
        }
#pragma unroll
        for (int m = 32; m >= 1; m >>= 1) {
            s  += __shfl_xor(s, m);
            s2 += __shfl_xor(s2, m);
        }
        if (lane == 0) {
            const int b = row >> 7;
            const int f = row & (F_DIM - 1);
            st[f * B_DIM + b]         = s;
            st[ST_SQ + f * B_DIM + b] = s2;
        }
    }
    cg::this_grid().sync();

    // ---- Phase 2: finalize scale/shift (blocks 0..127, f = blk) ----
    if (blk < F_DIM) {
        __shared__ float ssum[K_CLS], ssq[K_CLS];
        __shared__ int   cnt[K_CLS];
        if (tid < K_CLS) { ssum[tid] = 0.f; ssq[tid] = 0.f; cnt[tid] = 0; }
        __syncthreads();
        const int f = blk;
        for (int b = tid; b < B_DIM; b += 256) {
            const int k = labels[b];
            atomicAdd(&ssum[k], st[f * B_DIM + b]);
            atomicAdd(&ssq[k],  st[ST_SQ + f * B_DIM + b]);
            atomicAdd(&cnt[k], 1);
        }
        __syncthreads();
        if (tid < K_CLS) {
            const float c    = fmaxf((float)cnt[tid] * (float)L_DIM, 1.0f);
            const float mean = ssum[tid] / c;
            const float var  = ssq[tid] / c - mean * mean;
            const float inv  = rsqrtf(var + EPS);
            const float sc   = inv * weight[tid * F_DIM + f];
            st[ST_SCALE + tid * F_DIM + f] = sc;
            st[ST_SHIFT + tid * F_DIM + f] = bias[tid * F_DIM + f] - mean * sc;
        }
    }
    cg::this_grid().sync();

    // ---- Phase 3: apply own slice; x re-read should be MALL-hot ----
    const int b = r0 >> 7;                   // block-uniform
    const int k = labels[b];
#pragma unroll 4
    for (int it = 0; it < RPB; ++it) {
        const int row = r0 + it;
        const int f = row & (F_DIM - 1);
        const float sc = st[ST_SCALE + k * F_DIM + f];
        const float sh = st[ST_SHIFT + k * F_DIM + f];
        const size_t i4 = (size_t)row * (L_DIM / 4) + tid;
        vf4 v = reinterpret_cast<const vf4*>(x)[i4];
        vf4 o;
        o.x = v.x * sc + sh;
        o.y = v.y * sc + sh;
        o.z = v.z * sc + sh;
        o.w = v.w * sc + sh;
        __builtin_nontemporal_store(o, &reinterpret_cast<vf4*>(y)[i4]);
    }
}

extern "C" void kernel_launch(void* const* d_in, const int* in_sizes, int n_in,
                              void* d_out, int out_size, void* d_ws, size_t ws_size,
                              hipStream_t stream) {
    const float* x      = (const float*)d_in[0];
    const int*   labels = (const int*)d_in[1];
    const float* weight = (const float*)d_in[2];
    const float* bias   = (const float*)d_in[3];
    float* y  = (float*)d_out;
    float* st = (float*)d_ws;

    void* args[] = { (void*)&x, (void*)&labels, (void*)&weight, (void*)&bias,
                     (void*)&st, (void*)&y };
    hipLaunchCooperativeKernel((const void*)cbn_fused, dim3(GRID), dim3(256),
                               args, 0, stream);
}

// Round 8
// 133.978 us; speedup vs baseline: 2.6235x; 2.6235x over previous
//
#include <hip/hip_runtime.h>

#define B_DIM 512
#define F_DIM 128
#define L_DIM 1024
#define K_CLS 8
#define EPS 1e-5f
#define NROWS (B_DIM * F_DIM)          // 65536

typedef float vf4 __attribute__((ext_vector_type(4)));

// stats table in d_ws (floats): [0,1024) sum[k*F+f] | [1024,2048) sumsq[k*F+f]
#define ST_SQ (K_CLS * F_DIM)

// ---- Kernel A: per-row sums, one wave per row, atomicAdd into [k][f]. ----
// x loaded NORMALLY so it allocates in MALL (we re-read it in kernel B).
__global__ __launch_bounds__(256) void cbn_stats(const float* __restrict__ x,
                                                 const int* __restrict__ labels,
                                                 float* __restrict__ stats) {
    const int wave = threadIdx.x >> 6;
    const int lane = threadIdx.x & 63;
    const int row  = blockIdx.x * 4 + wave;    // [0, NROWS)
    const int b = row >> 7;
    const int f = row & (F_DIM - 1);

    const vf4* x4 = reinterpret_cast<const vf4*>(x) + (size_t)row * (L_DIM / 4);

    float s = 0.f, s2 = 0.f;
#pragma unroll
    for (int i = 0; i < 4; ++i) {
        vf4 v = x4[i * 64 + lane];
        s  += v.x + v.y + v.z + v.w;
        s2 += v.x * v.x + v.y * v.y + v.z * v.z + v.w * v.w;
    }
#pragma unroll
    for (int m = 32; m >= 1; m >>= 1) {
        s  += __shfl_xor(s, m);
        s2 += __shfl_xor(s2, m);
    }
    if (lane == 0) {
        const int k = labels[b];
        atomicAdd(&stats[k * F_DIM + f], s);
        atomicAdd(&stats[ST_SQ + k * F_DIM + f], s2);
    }
}

// ---- Kernel B: per-block finalize (own k, own 32 f's) + apply 32 rows. ----
// The kernel boundary is the grid sync; x re-read should hit MALL (R7 evidence).
#define RPB 32
__global__ __launch_bounds__(256) void cbn_final_apply(const float* __restrict__ x,
                                                       const int* __restrict__ labels,
                                                       const float* __restrict__ weight,
                                                       const float* __restrict__ bias,
                                                       const float* __restrict__ stats,
                                                       float* __restrict__ y) {
    const int tid = threadIdx.x;
    const int nBlocks = NROWS / RPB;                  // 2048
    const int blk = nBlocks - 1 - blockIdx.x;         // reversed: freshest MALL first
    const int r0 = blk * RPB;
    const int b0 = r0 >> 7;                           // 32 rows never cross a b boundary
    const int f0 = r0 & (F_DIM - 1);
    const int k  = labels[b0];

    __shared__ int   s_cnt;
    __shared__ float s_sc[RPB], s_sh[RPB];
    if (tid == 0) s_cnt = 0;
    __syncthreads();
    {
        int c = (labels[tid] == k) + (labels[tid + 256] == k);
#pragma unroll
        for (int m = 32; m >= 1; m >>= 1) c += __shfl_xor(c, m);
        if ((tid & 63) == 0) atomicAdd(&s_cnt, c);
    }
    __syncthreads();
    if (tid < RPB) {
        const int f = f0 + tid;
        const float cnt  = fmaxf((float)s_cnt * (float)L_DIM, 1.0f);
        const float mean = stats[k * F_DIM + f] / cnt;
        const float var  = stats[ST_SQ + k * F_DIM + f] / cnt - mean * mean;
        const float inv  = rsqrtf(var + EPS);
        const float sc   = inv * weight[k * F_DIM + f];
        s_sc[tid] = sc;
        s_sh[tid] = bias[k * F_DIM + f] - mean * sc;
    }
    __syncthreads();

#pragma unroll 8
    for (int it = 0; it < RPB; ++it) {
        const int row = r0 + it;
        const float sc = s_sc[it];
        const float sh = s_sh[it];
        const size_t i4 = (size_t)row * (L_DIM / 4) + tid;
        vf4 v = reinterpret_cast<const vf4*>(x)[i4];
        vf4 o;
        o.x = v.x * sc + sh;
        o.y = v.y * sc + sh;
        o.z = v.z * sc + sh;
        o.w = v.w * sc + sh;
        __builtin_nontemporal_store(o, &reinterpret_cast<vf4*>(y)[i4]);
    }
}

extern "C" void kernel_launch(void* const* d_in, const int* in_sizes, int n_in,
                              void* d_out, int out_size, void* d_ws, size_t ws_size,
                              hipStream_t stream) {
    const float* x      = (const float*)d_in[0];
    const int*   labels = (const int*)d_in[1];
    const float* weight = (const float*)d_in[2];
    const float* bias   = (const float*)d_in[3];
    float* y     = (float*)d_out;
    float* stats = (float*)d_ws;

    hipMemsetAsync(stats, 0, 2 * K_CLS * F_DIM * sizeof(float), stream);
    cbn_stats<<<NROWS / 4, 256, 0, stream>>>(x, labels, stats);
    cbn_final_apply<<<NROWS / RPB, 256, 0, stream>>>(x, labels, weight, bias, stats, y);
}

// Round 9
// 124.118 us; speedup vs baseline: 2.8319x; 1.0794x over previous
//
#include <hip/hip_runtime.h>
#include <hip/hip_cooperative_groups.h>

namespace cg = cooperative_groups;

#define B_DIM 512
#define F_DIM 128
#define L_DIM 1024
#define K_CLS 8
#define EPS 1e-5f
#define NROWS (B_DIM * F_DIM)     // 65536
#define GRID  2048
#define CHUNK 32                  // rows per phase-3 block

typedef float vf4 __attribute__((ext_vector_type(4)));

// st layout (floats): [0,NROWS) psum[f*512+b] | [NROWS,2N) psq
//                     [2N,+1024) scale[k*128+f] | [2N+1024,+1024) shift
#define ST_SQ    NROWS
#define ST_SCALE (2 * NROWS)
#define ST_SHIFT (2 * NROWS + K_CLS * F_DIM)

__global__ __launch_bounds__(256, 8) void cbn_fused(const float* __restrict__ x,
                                                    const int* __restrict__ labels,
                                                    const float* __restrict__ weight,
                                                    const float* __restrict__ bias,
                                                    float* __restrict__ st,
                                                    float* __restrict__ y) {
    const int tid  = threadIdx.x;
    const int wave = tid >> 6;
    const int lane = tid & 63;
    const int gw   = blockIdx.x * 4 + wave;   // global wave id
    const int NW   = GRID * 4;                // 8192 waves -> 8 rows/wave

    // ---- Phase 1: per-row partial sums, grid-stride, one row per wave-iter ----
    for (int row = gw; row < NROWS; row += NW) {
        const vf4* x4 = reinterpret_cast<const vf4*>(x) + (size_t)row * (L_DIM / 4);
        float s = 0.f, s2 = 0.f;
#pragma unroll
        for (int j = 0; j < 4; ++j) {
            vf4 v = x4[j * 64 + lane];        // normal load -> allocates in MALL
            s  += v.x + v.y + v.z + v.w;
            s2 += v.x * v.x + v.y * v.y + v.z * v.z + v.w * v.w;
        }
#pragma unroll
        for (int m = 32; m >= 1; m >>= 1) {
            s  += __shfl_xor(s, m);
            s2 += __shfl_xor(s2, m);
        }
        if (lane == 0) {
            const int b = row >> 7;
            const int f = row & (F_DIM - 1);
            st[f * B_DIM + b]         = s;
            st[ST_SQ + f * B_DIM + b] = s2;
        }
    }
    cg::this_grid().sync();

    // ---- Phase 2: blocks 0..127 finalize scale/shift for f = blockIdx.x ----
    if (blockIdx.x < F_DIM) {
        __shared__ float ssum[K_CLS], ssq[K_CLS];
        __shared__ int   cnt[K_CLS];
        if (tid < K_CLS) { ssum[tid] = 0.f; ssq[tid] = 0.f; cnt[tid] = 0; }
        __syncthreads();
        const int f = blockIdx.x;
        for (int b = tid; b < B_DIM; b += 256) {
            const int k = labels[b];
            atomicAdd(&ssum[k], st[f * B_DIM + b]);
            atomicAdd(&ssq[k],  st[ST_SQ + f * B_DIM + b]);
            atomicAdd(&cnt[k], 1);
        }
        __syncthreads();
        if (tid < K_CLS) {
            const float c    = fmaxf((float)cnt[tid] * (float)L_DIM, 1.0f);
            const float mean = ssum[tid] / c;
            const float var  = ssq[tid] / c - mean * mean;
            const float inv  = rsqrtf(var + EPS);
            const float sc   = inv * weight[tid * F_DIM + f];
            st[ST_SCALE + tid * F_DIM + f] = sc;
            st[ST_SHIFT + tid * F_DIM + f] = bias[tid * F_DIM + f] - mean * sc;
        }
    }
    cg::this_grid().sync();

    // ---- Phase 3: one 32-row chunk per block; x re-read hits MALL; NT y ----
    __shared__ float s_sc[CHUNK], s_sh[CHUNK];
    const int r0 = blockIdx.x * CHUNK;        // GRID*CHUNK == NROWS
    const int b  = r0 >> 7;                   // chunk stays within one b
    const int f0 = r0 & (F_DIM - 1);
    const int k  = labels[b];
    if (tid < CHUNK) {
        s_sc[tid] = st[ST_SCALE + k * F_DIM + f0 + tid];
        s_sh[tid] = st[ST_SHIFT + k * F_DIM + f0 + tid];
    }
    __syncthreads();
#pragma unroll 4
    for (int it = 0; it < CHUNK; ++it) {
        const int row = r0 + it;
        const float sc = s_sc[it];
        const float sh = s_sh[it];
        const size_t i4 = (size_t)row * (L_DIM / 4) + tid;
        vf4 v = reinterpret_cast<const vf4*>(x)[i4];
        vf4 o;
        o.x = v.x * sc + sh;
        o.y = v.y * sc + sh;
        o.z = v.z * sc + sh;
        o.w = v.w * sc + sh;
        __builtin_nontemporal_store(o, &reinterpret_cast<vf4*>(y)[i4]);
    }
}

// ================= Fallback path (R6 structure, proven 126.8 µs) =================
__global__ __launch_bounds__(256) void cbn_stats_fb(const float* __restrict__ x,
                                                    float* __restrict__ st) {
    const int wave = threadIdx.x >> 6;
    const int lane = threadIdx.x & 63;
    const int row  = blockIdx.x * 4 + wave;
    const int b = row >> 7;
    const int f = row & (F_DIM - 1);
    const vf4* x4 = reinterpret_cast<const vf4*>(x) + (size_t)row * (L_DIM / 4);
    float s = 0.f, s2 = 0.f;
#pragma unroll
    for (int i = 0; i < 4; ++i) {
        vf4 v = x4[i * 64 + lane];
        s  += v.x + v.y + v.z + v.w;
        s2 += v.x * v.x + v.y * v.y + v.z * v.z + v.w * v.w;
    }
#pragma unroll
    for (int m = 32; m >= 1; m >>= 1) {
        s  += __shfl_xor(s, m);
        s2 += __shfl_xor(s2, m);
    }
    if (lane == 0) {
        st[f * B_DIM + b]         = s;
        st[ST_SQ + f * B_DIM + b] = s2;
    }
}

__global__ __launch_bounds__(512) void cbn_finalize_fb(const int* __restrict__ labels,
                                                       const float* __restrict__ weight,
                                                       const float* __restrict__ bias,
                                                       float* __restrict__ st) {
    __shared__ float ssum[K_CLS], ssq[K_CLS];
    __shared__ int   cnt[K_CLS];
    const int f = blockIdx.x;
    const int b = threadIdx.x;
    if (b < K_CLS) { ssum[b] = 0.f; ssq[b] = 0.f; cnt[b] = 0; }
    __syncthreads();
    const int k = labels[b];
    atomicAdd(&ssum[k], st[f * B_DIM + b]);
    atomicAdd(&ssq[k],  st[ST_SQ + f * B_DIM + b]);
    atomicAdd(&cnt[k], 1);
    __syncthreads();
    if (b < K_CLS) {
        const float c = fmaxf((float)cnt[b] * (float)L_DIM, 1.0f);
        const float mean = ssum[b] / c;
        const float var  = ssq[b] / c - mean * mean;
        const float inv  = rsqrtf(var + EPS);
        const float sc   = inv * weight[b * F_DIM + f];
        st[ST_SCALE + b * F_DIM + f] = sc;
        st[ST_SHIFT + b * F_DIM + f] = bias[b * F_DIM + f] - mean * sc;
    }
}

#define APPLY_ROWS 4
__global__ __launch_bounds__(256) void cbn_apply_fb(const float* __restrict__ x,
                                                    const int* __restrict__ labels,
                                                    const float* __restrict__ st,
                                                    float* __restrict__ y) {
    const int nBlocks = NROWS / APPLY_ROWS;
    const int blk = nBlocks - 1 - blockIdx.x;
    const int row0 = blk * APPLY_ROWS;
#pragma unroll
    for (int it = 0; it < APPLY_ROWS; ++it) {
        const int row = row0 + it;
        const int b = row >> 7;
        const int f = row & (F_DIM - 1);
        const int k = labels[b];
        const float sc = st[ST_SCALE + k * F_DIM + f];
        const float sh = st[ST_SHIFT + k * F_DIM + f];
        const size_t i4 = (size_t)row * (L_DIM / 4) + threadIdx.x;
        vf4 v = reinterpret_cast<const vf4*>(x)[i4];
        vf4 o;
        o.x = v.x * sc + sh;
        o.y = v.y * sc + sh;
        o.z = v.z * sc + sh;
        o.w = v.w * sc + sh;
        __builtin_nontemporal_store(o, &reinterpret_cast<vf4*>(y)[i4]);
    }
}

extern "C" void kernel_launch(void* const* d_in, const int* in_sizes, int n_in,
                              void* d_out, int out_size, void* d_ws, size_t ws_size,
                              hipStream_t stream) {
    const float* x      = (const float*)d_in[0];
    const int*   labels = (const int*)d_in[1];
    const float* weight = (const float*)d_in[2];
    const float* bias   = (const float*)d_in[3];
    float* y  = (float*)d_out;
    float* st = (float*)d_ws;

    // Can the cooperative grid be fully co-resident? (host-side query, capture-safe)
    int blocksPerCU = 0;
    hipError_t qerr = hipOccupancyMaxActiveBlocksPerMultiprocessor(
        &blocksPerCU, (const void*)cbn_fused, 256, 0);
    const bool coop_ok = (qerr == hipSuccess) && (blocksPerCU * 256 >= GRID);

    if (coop_ok) {
        void* args[] = { (void*)&x, (void*)&labels, (void*)&weight, (void*)&bias,
                         (void*)&st, (void*)&y };
        hipLaunchCooperativeKernel((const void*)cbn_fused, dim3(GRID), dim3(256),
                                   args, 0, stream);
    } else {
        cbn_stats_fb<<<NROWS / 4, 256, 0, stream>>>(x, st);
        cbn_finalize_fb<<<F_DIM, 512, 0, stream>>>(labels, weight, bias, st);
        cbn_apply_fb<<<NROWS / APPLY_ROWS, 256, 0, stream>>>(x, labels, st, y);
    }
}

// Round 10
// 123.865 us; speedup vs baseline: 2.8377x; 1.0020x over previous
//
#include <hip/hip_runtime.h>
#include <hip/hip_cooperative_groups.h>

namespace cg = cooperative_groups;

#define B_DIM 512
#define F_DIM 128
#define L_DIM 1024
#define K_CLS 8
#define EPS 1e-5f
#define NROWS (B_DIM * F_DIM)     // 65536
#define GRID  2048
#define CHUNK 32                  // rows per block (contiguous, same b)

typedef float vf4 __attribute__((ext_vector_type(4)));

// stats table in d_ws (floats): [0,1024) sum[k*F+f] | [1024,2048) sumsq[k*F+f]
#define ST_SQ (K_CLS * F_DIM)

__global__ __launch_bounds__(256, 8) void cbn_fused(const float* __restrict__ x,
                                                    const int* __restrict__ labels,
                                                    const float* __restrict__ weight,
                                                    const float* __restrict__ bias,
                                                    float* __restrict__ stats,
                                                    float* __restrict__ y) {
    const int tid  = threadIdx.x;
    const int wave = tid >> 6;
    const int lane = tid & 63;
    const int r0   = blockIdx.x * CHUNK;      // 32 contiguous rows, same b
    const int b0   = r0 >> 7;
    const int f0   = r0 & (F_DIM - 1);
    const int k    = labels[b0];              // block-uniform

    // ---- Phase 1: row sums for own chunk -> atomicAdd into [k][f] table ----
    // wave w handles rows r0 + w*8 .. r0 + w*8 + 7
#pragma unroll
    for (int i = 0; i < CHUNK / 4 / 2; ++i) {   // 8 rows per wave
        const int row = r0 + wave * 8 + i;
        const vf4* x4 = reinterpret_cast<const vf4*>(x) + (size_t)row * (L_DIM / 4);
        float s = 0.f, s2 = 0.f;
#pragma unroll
        for (int j = 0; j < 4; ++j) {
            vf4 v = x4[j * 64 + lane];          // normal load -> allocates in MALL
            s  += v.x + v.y + v.z + v.w;
            s2 += v.x * v.x + v.y * v.y + v.z * v.z + v.w * v.w;
        }
#pragma unroll
        for (int m = 32; m >= 1; m >>= 1) {
            s  += __shfl_xor(s, m);
            s2 += __shfl_xor(s2, m);
        }
        if (lane == 0) {
            const int f = f0 + wave * 8 + i;
            atomicAdd(&stats[k * F_DIM + f], s);
            atomicAdd(&stats[ST_SQ + k * F_DIM + f], s2);
        }
    }
    cg::this_grid().sync();

    // ---- Phase 2+3 fused, fully parallel per block ----
    __shared__ int   s_cnt;
    __shared__ float s_sc[CHUNK], s_sh[CHUNK];
    if (tid == 0) s_cnt = 0;
    __syncthreads();
    {
        int c = (labels[tid] == k) + (labels[tid + 256] == k);
#pragma unroll
        for (int m = 32; m >= 1; m >>= 1) c += __shfl_xor(c, m);
        if (lane == 0) atomicAdd(&s_cnt, c);
    }
    __syncthreads();
    if (tid < CHUNK) {
        const int f = f0 + tid;
        const float cnt  = fmaxf((float)s_cnt * (float)L_DIM, 1.0f);
        const float mean = stats[k * F_DIM + f] / cnt;
        const float var  = stats[ST_SQ + k * F_DIM + f] / cnt - mean * mean;
        const float inv  = rsqrtf(var + EPS);
        const float sc   = inv * weight[k * F_DIM + f];
        s_sc[tid] = sc;
        s_sh[tid] = bias[k * F_DIM + f] - mean * sc;
    }
    __syncthreads();

    // apply own 32 rows; x re-read served by MALL; NT y stores
#pragma unroll 4
    for (int it = 0; it < CHUNK; ++it) {
        const int row = r0 + it;
        const float sc = s_sc[it];
        const float sh = s_sh[it];
        const size_t i4 = (size_t)row * (L_DIM / 4) + tid;
        vf4 v = reinterpret_cast<const vf4*>(x)[i4];
        vf4 o;
        o.x = v.x * sc + sh;
        o.y = v.y * sc + sh;
        o.z = v.z * sc + sh;
        o.w = v.w * sc + sh;
        __builtin_nontemporal_store(o, &reinterpret_cast<vf4*>(y)[i4]);
    }
}

// ================= Fallback path (R6 structure, proven 126.8 µs) =================
#define ST_SQ_FB    NROWS
#define ST_SCALE_FB (2 * NROWS)
#define ST_SHIFT_FB (2 * NROWS + K_CLS * F_DIM)

__global__ __launch_bounds__(256) void cbn_stats_fb(const float* __restrict__ x,
                                                    float* __restrict__ st) {
    const int wave = threadIdx.x >> 6;
    const int lane = threadIdx.x & 63;
    const int row  = blockIdx.x * 4 + wave;
    const int b = row >> 7;
    const int f = row & (F_DIM - 1);
    const vf4* x4 = reinterpret_cast<const vf4*>(x) + (size_t)row * (L_DIM / 4);
    float s = 0.f, s2 = 0.f;
#pragma unroll
    for (int i = 0; i < 4; ++i) {
        vf4 v = x4[i * 64 + lane];
        s  += v.x + v.y + v.z + v.w;
        s2 += v.x * v.x + v.y * v.y + v.z * v.z + v.w * v.w;
    }
#pragma unroll
    for (int m = 32; m >= 1; m >>= 1) {
        s  += __shfl_xor(s, m);
        s2 += __shfl_xor(s2, m);
    }
    if (lane == 0) {
        st[f * B_DIM + b]            = s;
        st[ST_SQ_FB + f * B_DIM + b] = s2;
    }
}

__global__ __launch_bounds__(512) void cbn_finalize_fb(const int* __restrict__ labels,
                                                       const float* __restrict__ weight,
                                                       const float* __restrict__ bias,
                                                       float* __restrict__ st) {
    __shared__ float ssum[K_CLS], ssq[K_CLS];
    __shared__ int   cnt[K_CLS];
    const int f = blockIdx.x;
    const int b = threadIdx.x;
    if (b < K_CLS) { ssum[b] = 0.f; ssq[b] = 0.f; cnt[b] = 0; }
    __syncthreads();
    const int k = labels[b];
    atomicAdd(&ssum[k], st[f * B_DIM + b]);
    atomicAdd(&ssq[k],  st[ST_SQ_FB + f * B_DIM + b]);
    atomicAdd(&cnt[k], 1);
    __syncthreads();
    if (b < K_CLS) {
        const float c = fmaxf((float)cnt[b] * (float)L_DIM, 1.0f);
        const float mean = ssum[b] / c;
        const float var  = ssq[b] / c - mean * mean;
        const float inv  = rsqrtf(var + EPS);
        const float sc   = inv * weight[b * F_DIM + f];
        st[ST_SCALE_FB + b * F_DIM + f] = sc;
        st[ST_SHIFT_FB + b * F_DIM + f] = bias[b * F_DIM + f] - mean * sc;
    }
}

#define APPLY_ROWS 4
__global__ __launch_bounds__(256) void cbn_apply_fb(const float* __restrict__ x,
                                                    const int* __restrict__ labels,
                                                    const float* __restrict__ st,
                                                    float* __restrict__ y) {
    const int nBlocks = NROWS / APPLY_ROWS;
    const int blk = nBlocks - 1 - blockIdx.x;
    const int row0 = blk * APPLY_ROWS;
#pragma unroll
    for (int it = 0; it < APPLY_ROWS; ++it) {
        const int row = row0 + it;
        const int b = row >> 7;
        const int f = row & (F_DIM - 1);
        const int k = labels[b];
        const float sc = st[ST_SCALE_FB + k * F_DIM + f];
        const float sh = st[ST_SHIFT_FB + k * F_DIM + f];
        const size_t i4 = (size_t)row * (L_DIM / 4) + threadIdx.x;
        vf4 v = reinterpret_cast<const vf4*>(x)[i4];
        vf4 o;
        o.x = v.x * sc + sh;
        o.y = v.y * sc + sh;
        o.z = v.z * sc + sh;
        o.w = v.w * sc + sh;
        __builtin_nontemporal_store(o, &reinterpret_cast<vf4*>(y)[i4]);
    }
}

extern "C" void kernel_launch(void* const* d_in, const int* in_sizes, int n_in,
                              void* d_out, int out_size, void* d_ws, size_t ws_size,
                              hipStream_t stream) {
    const float* x      = (const float*)d_in[0];
    const int*   labels = (const int*)d_in[1];
    const float* weight = (const float*)d_in[2];
    const float* bias   = (const float*)d_in[3];
    float* y  = (float*)d_out;
    float* ws = (float*)d_ws;

    int blocksPerCU = 0;
    hipError_t qerr = hipOccupancyMaxActiveBlocksPerMultiprocessor(
        &blocksPerCU, (const void*)cbn_fused, 256, 0);
    const bool coop_ok = (qerr == hipSuccess) && (blocksPerCU * 256 >= GRID);

    if (coop_ok) {
        // zero the 8 KiB [k][f] accumulator table
        hipMemsetAsync(ws, 0, 2 * K_CLS * F_DIM * sizeof(float), stream);
        void* args[] = { (void*)&x, (void*)&labels, (void*)&weight, (void*)&bias,
                         (void*)&ws, (void*)&y };
        hipLaunchCooperativeKernel((const void*)cbn_fused, dim3(GRID), dim3(256),
                                   args, 0, stream);
    } else {
        cbn_stats_fb<<<NROWS / 4, 256, 0, stream>>>(x, ws);
        cbn_finalize_fb<<<F_DIM, 512, 0, stream>>>(labels, weight, bias, ws);
        cbn_apply_fb<<<NROWS / APPLY_ROWS, 256, 0, stream>>>(x, labels, ws, y);
    }
}